// Round 1
// baseline (670.204 us; speedup 1.0000x reference)
//
#include <hip/hip_runtime.h>
#include <hip/hip_bf16.h>

#define HW_ 17
#define P_ 289            // 17*17
#define BIMG 128
#define CIN 256
#define CHID 1024

// ---- workspace layout (bytes) ----
#define WS_ZERO_OFF 0              // 1024 B zero page (also start of memset range)
#define WS_S_OFF    1024           // 128*289*4 = 147968 (f32 accumulator for s)
#define WS_W2_OFF   262144         // 9*1024*512*2 = 9437184
#define WS_X2_OFF   9699328        // 128*289*512*2 = 37879808  (end ~47.6 MB)

typedef __attribute__((ext_vector_type(8))) short short8;
typedef __attribute__((ext_vector_type(4))) float float4_t;

__device__ __forceinline__ unsigned short f32_to_bf16_rne(float f) {
  unsigned int u = __builtin_bit_cast(unsigned int, f);
  unsigned int r = (u + 0x7FFFu + ((u >> 16) & 1u)) >> 16;
  return (unsigned short)r;
}
__device__ __forceinline__ float bf16_bits_to_f32(unsigned short h) {
  unsigned int u = ((unsigned int)h) << 16;
  return __builtin_bit_cast(float, u);
}

__device__ __forceinline__ void glds16(const void* g, void* l) {
  __builtin_amdgcn_global_load_lds(
      (const __attribute__((address_space(1))) void*)g,
      (__attribute__((address_space(3))) void*)l, 16, 0, 0);
}

// ---- prep: w_rnn [1024][256][3][3] f32 -> w2 [9][1024][512] bf16 (hi|lo) ----
__global__ void prep_w_kernel(const float* __restrict__ w_rnn,
                              unsigned short* __restrict__ w2) {
  int t = blockIdx.x * 256 + threadIdx.x;   // 9*1024*256 total
  int c = t & 255;
  int oc = (t >> 8) & 1023;
  int kyx = t >> 18;                        // 0..8
  float w = w_rnn[(size_t)(oc * 256 + c) * 9 + kyx];
  unsigned short hi = f32_to_bf16_rne(w);
  unsigned short lo = f32_to_bf16_rne(w - bf16_bits_to_f32(hi));
  size_t base = (size_t)(kyx * 1024 + oc) * 512;
  w2[base + c] = hi;
  w2[base + 256 + c] = lo;
}

// ---- prep: x [128][256][17][17] f32 -> x2 [n][p][512] bf16 (hi|lo), LDS transpose ----
__global__ void prep_x_kernel(const float* __restrict__ x,
                              unsigned short* __restrict__ x2) {
  __shared__ unsigned short hibuf[P_ * 34];
  __shared__ unsigned short lobuf[P_ * 34];
  int n = blockIdx.y;
  int c0 = blockIdx.x * 32;
  int t = threadIdx.x;  // 256
  for (int ci = 0; ci < 32; ++ci) {
    const float* src = x + (size_t)(n * CIN + c0 + ci) * P_;
    for (int pb = 0; pb < 2; ++pb) {
      int p = pb * 256 + t;
      if (p < P_) {
        float v = src[p];
        unsigned short h = f32_to_bf16_rne(v);
        hibuf[p * 34 + ci] = h;
        lobuf[p * 34 + ci] = f32_to_bf16_rne(v - bf16_bits_to_f32(h));
      }
    }
  }
  __syncthreads();
  int ci = t & 31;
  int psub = t >> 5;  // 0..7
  for (int pb = 0; pb < P_; pb += 8) {
    int p = pb + psub;
    if (p < P_) {
      size_t ob = ((size_t)n * P_ + p) * 512;
      x2[ob + c0 + ci]       = hibuf[p * 34 + ci];
      x2[ob + 256 + c0 + ci] = lobuf[p * 34 + ci];
    }
  }
}

// ---- conv: implicit GEMM, 9 taps x 12 virtual-K chunks, bf16 hi/lo 3-product ----
#define BM 128
#define BN 160
#define LDS_B_OFF 16384               // A tile: 128*64*2
#define LDS_TOTAL (16384 + 20480)     // + B tile: 160*64*2

__global__ __launch_bounds__(256, 2) void conv_kernel(
    const unsigned short* __restrict__ w2,   // [9][1024][512]
    const unsigned short* __restrict__ x2,   // [128*289][512]
    const float* __restrict__ b_rnn,
    const float* __restrict__ w_out,
    const char* __restrict__ zpage,
    float* __restrict__ sbuf) {
  __shared__ char lds[LDS_TOTAL];
  int t = threadIdx.x;
  int n = blockIdx.z;        // image
  int mb = blockIdx.x;       // 0..7  -> oc block
  int nb = blockIdx.y;       // 0..1  -> pos block
  int oc0 = mb * BM;
  int pos0 = nb * BN;

  // ---------- staging geometry ----------
  int cc = t & 7;            // 16B chunk within a 128B row
  int rr = t >> 3;           // 0..31 base row (A and B both step by 32 rows/issue)
  int sA = cc ^ (rr & 7);    // inverse swizzle on SOURCE (rule #21)
  int sB = sA;               // same formula (rows step by 32 -> row&7 invariant)

  int pIdx[5], pyA[5], pxA[5];
#pragma unroll
  for (int i = 0; i < 5; ++i) {
    int p = pos0 + rr + 32 * i;
    pIdx[i] = p;
    int py = p / 17;
    pyA[i] = py;
    pxA[i] = p - py * 17;
  }

  const char* w2c = (const char*)w2;
  const char* x2c = (const char*)x2;
  char* ldsA_w = lds + (size_t)(t & ~63) * 16;               // wave-uniform base
  char* ldsB_w = lds + LDS_B_OFF + (size_t)(t & ~63) * 16;

  // ---------- mfma geometry ----------
  int lane = t & 63;
  int wid = t >> 6;          // 0..3
  int wm = wid >> 1;         // 0..1
  int wn = wid & 1;          // 0..1
  int lrow = lane & 15;
  int g = lane >> 4;
  int aoff[4], boff[5];
#pragma unroll
  for (int m = 0; m < 4; ++m) {
    int row = wm * 64 + m * 16 + lrow;
    aoff[m] = row * 128 + ((g * 16) ^ ((row & 7) << 4));
  }
#pragma unroll
  for (int nf = 0; nf < 5; ++nf) {
    int row = wn * 80 + nf * 16 + lrow;
    boff[nf] = LDS_B_OFF + row * 128 + ((g * 16) ^ ((row & 7) << 4));
  }

  float4_t acc[4][5];
#pragma unroll
  for (int m = 0; m < 4; ++m)
#pragma unroll
    for (int nf = 0; nf < 5; ++nf)
      acc[m][nf] = (float4_t){0.f, 0.f, 0.f, 0.f};

  for (int kyx = 0; kyx < 9; ++kyx) {
    int ky = kyx / 3, kx = kyx - 3 * ky;
    const char* pB[5];
#pragma unroll
    for (int i = 0; i < 5; ++i) {
      int yy = pyA[i] + ky - 1;
      int xx = pxA[i] + kx - 1;
      bool ok = (pIdx[i] < P_) && (yy >= 0) && (yy < 17) && (xx >= 0) && (xx < 17);
      pB[i] = ok ? x2c + 2 * (((size_t)(n * P_ + yy * 17 + xx)) * 512 + sB * 8)
                 : (const char*)zpage;
    }
    const char* pA = w2c + 2 * (((size_t)(kyx * 1024 + oc0 + rr)) * 512 + sA * 8);

    for (int ck = 0; ck < 12; ++ck) {
      // virtual K chunk -> physical hi/lo chunks (3-product scheme)
      int ckA = (ck < 4) ? ck : ck - 4;   // w: hi,hi,lo
      int ckB = (ck < 8) ? ck : ck - 8;   // x: hi,lo,hi
      const char* a = pA + ckA * 128;
      glds16(a,             ldsA_w);
      glds16(a + 32768,     ldsA_w + 4096);   // +32 rows * 512ch * 2B
      glds16(a + 65536,     ldsA_w + 8192);
      glds16(a + 98304,     ldsA_w + 12288);
      int bo = ckB * 128;
      glds16(pB[0] + bo, ldsB_w);
      glds16(pB[1] + bo, ldsB_w + 4096);
      glds16(pB[2] + bo, ldsB_w + 8192);
      glds16(pB[3] + bo, ldsB_w + 12288);
      glds16(pB[4] + bo, ldsB_w + 16384);
      __syncthreads();
#pragma unroll
      for (int ks = 0; ks < 2; ++ks) {
        int kx2 = ks << 6;
        short8 af[4], bf[5];
#pragma unroll
        for (int m = 0; m < 4; ++m)
          af[m] = *(const short8*)(lds + (aoff[m] ^ kx2));
#pragma unroll
        for (int nf = 0; nf < 5; ++nf)
          bf[nf] = *(const short8*)(lds + (boff[nf] ^ kx2));
#pragma unroll
        for (int m = 0; m < 4; ++m)
#pragma unroll
          for (int nf = 0; nf < 5; ++nf)
            acc[m][nf] = __builtin_amdgcn_mfma_f32_16x16x32_bf16(
                af[m], bf[nf], acc[m][nf], 0, 0, 0);
      }
      __syncthreads();
    }
  }

  // ---------- epilogue: +b_rnn, tanh, relu, dot w_out, reduce, atomic ----------
  float sacc[5] = {0.f, 0.f, 0.f, 0.f, 0.f};
#pragma unroll
  for (int m = 0; m < 4; ++m) {
#pragma unroll
    for (int r = 0; r < 4; ++r) {
      int oc = oc0 + wm * 64 + m * 16 + g * 4 + r;
      float wo = w_out[oc];
      float br = b_rnn[oc];
#pragma unroll
      for (int nf = 0; nf < 5; ++nf) {
        float v = acc[m][nf][r] + br;
        float h = tanhf(v);
        h = fmaxf(h, 0.f);
        sacc[nf] = fmaf(wo, h, sacc[nf]);
      }
    }
  }
#pragma unroll
  for (int nf = 0; nf < 5; ++nf) {
    sacc[nf] += __shfl_xor(sacc[nf], 16);
    sacc[nf] += __shfl_xor(sacc[nf], 32);
  }
  if (lane < 16) {
#pragma unroll
    for (int nf = 0; nf < 5; ++nf) {
      int pos = pos0 + wn * 80 + nf * 16 + lrow;
      if (pos < P_) atomicAdd(&sbuf[n * P_ + pos], sacc[nf]);
    }
  }
}

// ---- finalize: sigmoid + write score + first-occurrence argmax -> (y,x) floats ----
__global__ void finalize_kernel(const float* __restrict__ sbuf,
                                const float* __restrict__ b_out,
                                float* __restrict__ out) {
  int n = blockIdx.x;
  int lane = threadIdx.x;  // 64
  float bo = b_out[0];
  float vmax = -1e30f;
  int imax = 0x7FFFFFFF;
  for (int p = lane; p < P_; p += 64) {
    float v = sbuf[n * P_ + p] + bo;
    float sg = 1.0f / (1.0f + expf(-v));
    out[n * P_ + p] = sg;
    if (sg > vmax) { vmax = sg; imax = p; }  // strict > keeps first occurrence
  }
  for (int off = 32; off >= 1; off >>= 1) {
    float ov = __shfl_xor(vmax, off);
    int oi = __shfl_xor(imax, off);
    if (ov > vmax || (ov == vmax && oi < imax)) { vmax = ov; imax = oi; }
  }
  if (lane == 0) {
    int y = imax / 17;
    int xq = imax - y * 17;
    out[BIMG * P_ + n * 2 + 0] = (float)y;
    out[BIMG * P_ + n * 2 + 1] = (float)xq;
  }
}

extern "C" void kernel_launch(void* const* d_in, const int* in_sizes, int n_in,
                              void* d_out, int out_size, void* d_ws, size_t ws_size,
                              hipStream_t stream) {
  const float* x     = (const float*)d_in[0];
  const float* w_rnn = (const float*)d_in[1];
  const float* b_rnn = (const float*)d_in[2];
  const float* w_out = (const float*)d_in[3];
  const float* b_out = (const float*)d_in[4];
  char* ws = (char*)d_ws;
  unsigned short* w2 = (unsigned short*)(ws + WS_W2_OFF);
  unsigned short* x2 = (unsigned short*)(ws + WS_X2_OFF);
  float* sbuf = (float*)(ws + WS_S_OFF);
  float* out = (float*)d_out;

  // zero page + s accumulator (ws is re-poisoned to 0xAA before every launch)
  hipMemsetAsync(ws, 0, WS_S_OFF + BIMG * P_ * 4, stream);
  prep_w_kernel<<<9216, 256, 0, stream>>>(w_rnn, w2);
  prep_x_kernel<<<dim3(8, 128), 256, 0, stream>>>(x, x2);
  conv_kernel<<<dim3(8, 2, 128), 256, 0, stream>>>(w2, x2, b_rnn, w_out, ws, sbuf);
  finalize_kernel<<<128, 64, 0, stream>>>(sbuf, b_out, out);
}

// Round 5
// 611.611 us; speedup vs baseline: 1.0958x; 1.0958x over previous
//
#include <hip/hip_runtime.h>
#include <hip/hip_bf16.h>

#define HW_ 17
#define P_ 289            // 17*17
#define BIMG 128
#define CIN 256
#define CHID 1024

// ---- workspace layout (bytes) ----
#define WS_S_OFF    1024           // 128*289*4 f32 accumulator for s
#define WS_W2_OFF   262144         // 9*1024*512*2 = 9437184
#define WS_X2_OFF   9699328        // 128*289*512*2 = 37879808

typedef __attribute__((ext_vector_type(8))) short short8;
typedef __attribute__((ext_vector_type(4))) float float4_t;

// ---- LDS map (dynamic, 80 KB/block -> 2 blocks/CU) ----
#define BHALO_OFF  0
#define BHALO_ROWS 384             // 19*19=361 used, staged to 384
#define ABUF_OFF   49152           // 384*128
#define ABUF_SZ    16384           // 128 rows * 128 B
#define LDS_TOTAL  81920

__device__ __forceinline__ unsigned short f32_to_bf16_rne(float f) {
  unsigned int u = __builtin_bit_cast(unsigned int, f);
  unsigned int r = (u + 0x7FFFu + ((u >> 16) & 1u)) >> 16;
  return (unsigned short)r;
}
__device__ __forceinline__ float bf16_bits_to_f32(unsigned short h) {
  unsigned int u = ((unsigned int)h) << 16;
  return __builtin_bit_cast(float, u);
}
__device__ __forceinline__ void glds16(const void* g, void* l) {
  __builtin_amdgcn_global_load_lds(
      (const __attribute__((address_space(1))) void*)g,
      (__attribute__((address_space(3))) void*)l, 16, 0, 0);
}

// ---- prep: w_rnn [1024][256][3][3] f32 -> w2 [9][1024][512] bf16 (hi|lo) ----
__global__ void prep_w_kernel(const float* __restrict__ w_rnn,
                              unsigned short* __restrict__ w2) {
  int t = blockIdx.x * 256 + threadIdx.x;   // 9*1024*256 total
  int c = t & 255;
  int oc = (t >> 8) & 1023;
  int kyx = t >> 18;                        // 0..8
  float w = w_rnn[(size_t)(oc * 256 + c) * 9 + kyx];
  unsigned short hi = f32_to_bf16_rne(w);
  unsigned short lo = f32_to_bf16_rne(w - bf16_bits_to_f32(hi));
  size_t base = (size_t)(kyx * 1024 + oc) * 512;
  w2[base + c] = hi;
  w2[base + 256 + c] = lo;
}

// ---- prep: x [128][256][17][17] f32 -> x2 [n][p][512] bf16 (hi|lo) ----
__global__ void prep_x_kernel(const float* __restrict__ x,
                              unsigned short* __restrict__ x2) {
  __shared__ unsigned short hibuf[P_ * 34];
  __shared__ unsigned short lobuf[P_ * 34];
  int n = blockIdx.y;
  int c0 = blockIdx.x * 32;
  int t = threadIdx.x;  // 256
  for (int ci = 0; ci < 32; ++ci) {
    const float* src = x + (size_t)(n * CIN + c0 + ci) * P_;
    for (int pb = 0; pb < 2; ++pb) {
      int p = pb * 256 + t;
      if (p < P_) {
        float v = src[p];
        unsigned short h = f32_to_bf16_rne(v);
        hibuf[p * 34 + ci] = h;
        lobuf[p * 34 + ci] = f32_to_bf16_rne(v - bf16_bits_to_f32(h));
      }
    }
  }
  __syncthreads();
  int ci = t & 31;
  int psub = t >> 5;  // 0..7
  for (int pb = 0; pb < P_; pb += 8) {
    int p = pb + psub;
    if (p < P_) {
      size_t ob = ((size_t)n * P_ + p) * 512;
      x2[ob + c0 + ci]       = hibuf[p * 34 + ci];
      x2[ob + 256 + c0 + ci] = lobuf[p * 34 + ci];
    }
  }
}

// ---- conv: implicit GEMM, B-halo resident in LDS, counted-vmcnt pipeline ----
// grid (8 mb, 128 n), 256 threads (4 waves, 2M x 2N), wave tile 64 oc x 160 pos.
// 108 steps: 8 segments (one per physical 64-ch B chunk), taps inner.
//   seg 0..3 : B = H chunk seg, A products {H, L}  (18 tap-steps)
//   seg 4..7 : B = L chunk seg-4, A product {H}    (9 tap-steps)
__global__ __launch_bounds__(256, 2) void conv_kernel(
    const unsigned short* __restrict__ w2,   // [9][1024][512]
    const unsigned short* __restrict__ x2,   // [128*289][512]
    const float* __restrict__ b_rnn,
    const float* __restrict__ w_out,
    const char* __restrict__ zpage,
    float* __restrict__ sbuf) {
  extern __shared__ char lds[];
  const int t = threadIdx.x;
  const int n = blockIdx.y;
  const int oc0 = blockIdx.x * 128;

  const int lane = t & 63;
  const int wid = t >> 6;
  const int wm = wid >> 1, wn = wid & 1;
  const int lrow = lane & 15, g = lane >> 4;

  // ---------- staging geometry ----------
  const int cc = t & 7;            // 16B unit within 128B row
  const int rr = t >> 3;           // 0..31 row within a 32-row issue group
  const int sw = cc ^ (rr & 7);    // inverse-swizzled source unit (rule #21)

  const char* w2c = (const char*)w2;
  const char* x2c = (const char*)x2;
  const size_t aLaneBase = (size_t)(oc0 + rr) * 1024 + sw * 16;
  char* aDst = lds + ABUF_OFF + (t & ~63) * 16;
  char* bDst = lds + BHALO_OFF + (t & ~63) * 16;

  // B-halo per-call source offsets (seg-independent part)
  int pBase[12];
#pragma unroll
  for (int i = 0; i < 12; ++i) {
    int h = i * 32 + rr;                 // halo row this lane stages, < 384
    int hy = h / 19, hx = h - hy * 19;
    bool interior = (h < 361) && (hy >= 1) && (hy <= 17) && (hx >= 1) && (hx <= 17);
    int p = (hy - 1) * 17 + (hx - 1);
    pBase[i] = interior ? (int)((size_t)(n * P_ + p) * 1024 + sw * 16) : -1;
  }

  // ---------- mfma read geometry ----------
  int aoff[4][2];
#pragma unroll
  for (int i = 0; i < 4; ++i) {
    int row = wm * 64 + i * 16 + lrow;
#pragma unroll
    for (int kk = 0; kk < 2; ++kk)
      aoff[i][kk] = ABUF_OFF + row * 128 + ((kk * 64 + g * 16) ^ ((row & 7) << 4));
  }
  int hb[10];
#pragma unroll
  for (int j = 0; j < 10; ++j) {
    int p = wn * 160 + j * 16 + lrow;
    int py = p / 17;
    hb[j] = (p < P_) ? py * 19 + (p - py * 17) : 0;
  }

  float4_t acc[4][10];
#pragma unroll
  for (int i = 0; i < 4; ++i)
#pragma unroll
    for (int j = 0; j < 10; ++j) acc[i][j] = (float4_t){0.f, 0.f, 0.f, 0.f};

  // prologue: stage A for step 0 (seg0, product H, tap0 -> chunk 0) into buf 0
  {
    const char* src = w2c + aLaneBase;
#pragma unroll
    for (int i = 0; i < 4; ++i) glds16(src + i * 32768, aDst + i * 4096);
  }

  for (int s = 0; s < 108; ++s) {
    int seg, rep, tap;
    if (s < 72) { seg = s / 18; int r = s - seg * 18; rep = r / 9; tap = r - rep * 9; }
    else        { int q = s - 72; seg = 4 + q / 9; rep = 0; tap = q - (seg - 4) * 9; }

    // B-halo stage at segment start (12 issues; B phys chunk == seg)
    if (rep == 0 && tap == 0) {
#pragma unroll
      for (int i = 0; i < 12; ++i) {
        const char* src = (pBase[i] >= 0) ? x2c + pBase[i] + seg * 128 : zpage;
        glds16(src, bDst + i * 4096);
      }
    }
    // A prefetch for step s+1 (4 issues), then counted wait
    if (s < 107) {
      int s1 = s + 1, seg1, rep1, tap1;
      if (s1 < 72) { seg1 = s1 / 18; int r = s1 - seg1 * 18; rep1 = r / 9; tap1 = r - rep1 * 9; }
      else         { int q = s1 - 72; seg1 = 4 + q / 9; rep1 = 0; tap1 = q - (seg1 - 4) * 9; }
      int aChunk1 = (seg1 < 4) ? (rep1 ? 4 + seg1 : seg1) : (seg1 - 4);
      const char* src = w2c + aLaneBase + (size_t)tap1 * 1048576 + aChunk1 * 128;
      char* dst = aDst + ((s1 & 1) ? ABUF_SZ : 0);
#pragma unroll
      for (int i = 0; i < 4; ++i) glds16(src + i * 32768, dst + i * 4096);
      asm volatile("s_waitcnt vmcnt(4)" ::: "memory");   // retire A(s) [+ B12 at seg start]
    } else {
      asm volatile("s_waitcnt vmcnt(0)" ::: "memory");
    }
    __builtin_amdgcn_s_barrier();

    const int d = (tap / 3) * 19 + (tap - (tap / 3) * 3);
    const int abase = (s & 1) ? ABUF_SZ : 0;
    __builtin_amdgcn_s_setprio(1);
#pragma unroll
    for (int kk = 0; kk < 2; ++kk) {
      short8 af[4];
#pragma unroll
      for (int i = 0; i < 4; ++i)
        af[i] = *(const short8*)(lds + abase + aoff[i][kk]);
#pragma unroll
      for (int jh = 0; jh < 2; ++jh) {
        short8 bf[5];
#pragma unroll
        for (int j5 = 0; j5 < 5; ++j5) {
          int h = hb[jh * 5 + j5] + d;
          int boff = h * 128 + ((kk * 64 + g * 16) ^ ((h & 7) << 4));
          bf[j5] = *(const short8*)(lds + boff);
        }
#pragma unroll
        for (int i = 0; i < 4; ++i)
#pragma unroll
          for (int j5 = 0; j5 < 5; ++j5)
            acc[i][jh * 5 + j5] = __builtin_amdgcn_mfma_f32_16x16x32_bf16(
                af[i], bf[j5], acc[i][jh * 5 + j5], 0, 0, 0);
      }
    }
    __builtin_amdgcn_s_setprio(0);
    __builtin_amdgcn_s_barrier();
    asm volatile("" ::: "memory");
  }

  // ---------- epilogue: +b_rnn, tanh, relu, dot w_out, reduce, atomic ----------
  float sacc[10] = {0.f, 0.f, 0.f, 0.f, 0.f, 0.f, 0.f, 0.f, 0.f, 0.f};
#pragma unroll
  for (int i = 0; i < 4; ++i) {
#pragma unroll
    for (int r = 0; r < 4; ++r) {
      int oc = oc0 + wm * 64 + i * 16 + g * 4 + r;
      float wo = w_out[oc];
      float br = b_rnn[oc];
#pragma unroll
      for (int j = 0; j < 10; ++j) {
        float v = acc[i][j][r] + br;
        float h = tanhf(v);
        h = fmaxf(h, 0.f);
        sacc[j] = fmaf(wo, h, sacc[j]);
      }
    }
  }
#pragma unroll
  for (int j = 0; j < 10; ++j) {
    sacc[j] += __shfl_xor(sacc[j], 16);
    sacc[j] += __shfl_xor(sacc[j], 32);
  }
  if (lane < 16) {
#pragma unroll
    for (int j = 0; j < 10; ++j) {
      int pos = wn * 160 + j * 16 + lrow;
      if (pos < P_) atomicAdd(&sbuf[n * P_ + pos], sacc[j]);
    }
  }
}

// ---- finalize: sigmoid + write score + first-occurrence argmax -> (y,x) floats ----
__global__ void finalize_kernel(const float* __restrict__ sbuf,
                                const float* __restrict__ b_out,
                                float* __restrict__ out) {
  int n = blockIdx.x;
  int lane = threadIdx.x;  // 64
  float bo = b_out[0];
  float vmax = -1e30f;
  int imax = 0x7FFFFFFF;
  for (int p = lane; p < P_; p += 64) {
    float v = sbuf[n * P_ + p] + bo;
    float sg = 1.0f / (1.0f + expf(-v));
    out[n * P_ + p] = sg;
    if (sg > vmax) { vmax = sg; imax = p; }  // strict > keeps first occurrence
  }
  for (int off = 32; off >= 1; off >>= 1) {
    float ov = __shfl_xor(vmax, off);
    int oi = __shfl_xor(imax, off);
    if (ov > vmax || (ov == vmax && oi < imax)) { vmax = ov; imax = oi; }
  }
  if (lane == 0) {
    int y = imax / 17;
    int xq = imax - y * 17;
    out[BIMG * P_ + n * 2 + 0] = (float)y;
    out[BIMG * P_ + n * 2 + 1] = (float)xq;
  }
}

extern "C" void kernel_launch(void* const* d_in, const int* in_sizes, int n_in,
                              void* d_out, int out_size, void* d_ws, size_t ws_size,
                              hipStream_t stream) {
  const float* x     = (const float*)d_in[0];
  const float* w_rnn = (const float*)d_in[1];
  const float* b_rnn = (const float*)d_in[2];
  const float* w_out = (const float*)d_in[3];
  const float* b_out = (const float*)d_in[4];
  char* ws = (char*)d_ws;
  unsigned short* w2 = (unsigned short*)(ws + WS_W2_OFF);
  unsigned short* x2 = (unsigned short*)(ws + WS_X2_OFF);
  float* sbuf = (float*)(ws + WS_S_OFF);
  float* out = (float*)d_out;

  // host-side, non-stream call: safe under graph capture, same work every call
  hipFuncSetAttribute((const void*)conv_kernel,
                      hipFuncAttributeMaxDynamicSharedMemorySize, LDS_TOTAL);

  // zero page + s accumulator (ws is re-poisoned to 0xAA before every launch)
  hipMemsetAsync(ws, 0, WS_S_OFF + BIMG * P_ * 4, stream);
  prep_w_kernel<<<9216, 256, 0, stream>>>(w_rnn, w2);
  prep_x_kernel<<<dim3(8, 128), 256, 0, stream>>>(x, x2);
  conv_kernel<<<dim3(8, 128), 256, LDS_TOTAL, stream>>>(w2, x2, b_rnn, w_out, ws, sbuf);
  finalize_kernel<<<128, 64, 0, stream>>>(sbuf, b_out, out);
}